// Round 1
// baseline (359.296 us; speedup 1.0000x reference)
//
#include <hip/hip_runtime.h>
#include <stdint.h>

#define DIM   2048
#define NH    32
#define NKV   8
#define HD    64
#define BATCH 2
#define SEQ   2048

typedef __attribute__((ext_vector_type(8))) short  short8;
typedef __attribute__((ext_vector_type(4))) short  short4v;
typedef __attribute__((ext_vector_type(4))) float  f32x4;

static __device__ __forceinline__ short f2bf(float f) {
  union { float f; uint32_t u; } v; v.f = f;
  uint32_t r = v.u + 0x7FFFu + ((v.u >> 16) & 1u);
  return (short)(r >> 16);
}

#define GLD16(gp, lp) __builtin_amdgcn_global_load_lds(                      \
    (__attribute__((address_space(1))) void*)(void*)(gp),                    \
    (__attribute__((address_space(3))) void*)(lp), 16, 0, 0)

// ---------------- prep kernels ----------------

__global__ void cvt_x_kernel(const float* __restrict__ in, short* __restrict__ out, int n4) {
  int i = blockIdx.x * blockDim.x + threadIdx.x;
  if (i < n4) {
    f32x4 v = *reinterpret_cast<const f32x4*>(in + (size_t)i * 4);
    short4v o;
    o.x = f2bf(v.x); o.y = f2bf(v.y); o.z = f2bf(v.z); o.w = f2bf(v.w);
    *reinterpret_cast<short4v*>(out + (size_t)i * 4) = o;
  }
}

// in: [R][C] f32  ->  out: [C][R] bf16
__global__ void transpose_bf_kernel(const float* __restrict__ in, short* __restrict__ out,
                                    int R, int C) {
  __shared__ float t[32][33];
  int c0 = blockIdx.x * 32, r0 = blockIdx.y * 32;
  int tx = threadIdx.x, ty = threadIdx.y;  // (32, 8)
#pragma unroll
  for (int j = 0; j < 32; j += 8)
    t[ty + j][tx] = in[(size_t)(r0 + ty + j) * C + c0 + tx];
  __syncthreads();
#pragma unroll
  for (int j = 0; j < 32; j += 8)
    out[(size_t)(c0 + ty + j) * R + r0 + tx] = f2bf(t[tx][ty + j]);
}

__global__ void rope_tab_kernel(float* __restrict__ ct, float* __restrict__ st) {
  int i = blockIdx.x * blockDim.x + threadIdx.x;  // SEQ*32
  if (i < SEQ * 32) {
    int pos = i >> 5, f = i & 31;
    float inv = powf(10000.0f, -(float)f / 32.0f);
    float th = (float)pos * inv;
    ct[i] = cosf(th);
    st[i] = sinf(th);
  }
}

// ---------------- GEMM: C[M][N] = A[M][K] * Bt[N][K]^T  (bf16 in, f32 acc) ----------------
// MODE 0: store f32 to out[M][DIM]            (O-projection)
// MODE 1: RoPE + *0.125, bf16 -> q_ws[b][h][s][d]
// MODE 2: RoPE,          bf16 -> k_ws[b][kvh][s][d]
// MODE 3: plain,         bf16 -> v_ws[b][kvh][d][s]   (transposed)
template <int MODE>
__global__ void __launch_bounds__(256)
gemm_bf_kernel(const short* __restrict__ A, const short* __restrict__ Bt,
               void* __restrict__ out,
               const float* __restrict__ ct, const float* __restrict__ st) {
  __shared__ __align__(16) short As[4096];  // [128][32]
  __shared__ __align__(16) short Bs[4096];  // [128][32]
  const int tid = threadIdx.x;
  const int w = tid >> 6, l = tid & 63;
  const int lg = l >> 4, lr = l & 15;
  const int wr = w >> 1, wc = w & 1;
  const int m0 = blockIdx.y * 128, n0 = blockIdx.x * 128;

  // staging: chunk c -> row=c>>2, 16B-unit=c&3, source unit pre-swizzled by row&3
  const int cA0 = tid, cA1 = tid + 256;
  const int rA0 = cA0 >> 2, kA0 = ((cA0 & 3) ^ (rA0 & 3)) << 3;
  const int rA1 = cA1 >> 2, kA1 = ((cA1 & 3) ^ (rA1 & 3)) << 3;
  const short* gA0 = A + (size_t)(m0 + rA0) * DIM + kA0;
  const short* gA1 = A + (size_t)(m0 + rA1) * DIM + kA1;
  const short* gB0 = Bt + (size_t)(n0 + rA0) * DIM + kA0;
  const short* gB1 = Bt + (size_t)(n0 + rA1) * DIM + kA1;
  short* lA0 = As + w * 512;
  short* lA1 = As + 2048 + w * 512;
  short* lB0 = Bs + w * 512;
  short* lB1 = Bs + 2048 + w * 512;

  f32x4 acc[4][4] = {};

  for (int k0 = 0; k0 < DIM; k0 += 32) {
    GLD16(gA0 + k0, lA0);
    GLD16(gA1 + k0, lA1);
    GLD16(gB0 + k0, lB0);
    GLD16(gB1 + k0, lB1);
    __syncthreads();
    short8 af[4], bq[4];
#pragma unroll
    for (int mt = 0; mt < 4; ++mt) {
      int row = wr * 64 + mt * 16 + lr;
      af[mt] = *(const short8*)&As[row * 32 + ((lg ^ (row & 3)) << 3)];
    }
#pragma unroll
    for (int nt = 0; nt < 4; ++nt) {
      int row = wc * 64 + nt * 16 + lr;
      bq[nt] = *(const short8*)&Bs[row * 32 + ((lg ^ (row & 3)) << 3)];
    }
#pragma unroll
    for (int mt = 0; mt < 4; ++mt)
#pragma unroll
      for (int nt = 0; nt < 4; ++nt)
        acc[mt][nt] = __builtin_amdgcn_mfma_f32_16x16x32_bf16(af[mt], bq[nt], acc[mt][nt], 0, 0, 0);
    __syncthreads();
  }

  const int mrow0 = m0 + wr * 64;
  const int ncol0 = n0 + wc * 64;
#pragma unroll
  for (int mt = 0; mt < 4; ++mt)
#pragma unroll
    for (int nt = 0; nt < 4; ++nt)
#pragma unroll
      for (int i = 0; i < 4; ++i) {
        int m = mrow0 + mt * 16 + lg * 4 + i;
        int n = ncol0 + nt * 16 + lr;
        float v = acc[mt][nt][i];
        if (MODE == 0) {
          ((float*)out)[(size_t)m * DIM + n] = v;
        } else if (MODE == 3) {
          int b = m >> 11, s = m & (SEQ - 1);
          int h = n >> 6, d = n & 63;
          ((short*)out)[((size_t)(b * NKV + h) * HD + d) * SEQ + s] = f2bf(v);
        } else {
          float p = __shfl_xor(v, 1);
          int b = m >> 11, s = m & (SEQ - 1);
          int h = n >> 6, d = n & 63;
          float cs = ct[(s << 5) + (d >> 1)];
          float sn = st[(s << 5) + (d >> 1)];
          float r = ((d & 1) == 0) ? (v * cs - p * sn) : (p * sn + v * cs);
          if (MODE == 1) {
            r *= 0.125f;  // 1/sqrt(HD)
            ((short*)out)[((size_t)(b * NH + h) * SEQ + s) * HD + d] = f2bf(r);
          } else {
            ((short*)out)[((size_t)(b * NKV + h) * SEQ + s) * HD + d] = f2bf(r);
          }
        }
      }
}

// ---------------- flash attention (swapped QK^T, GQA, causal) ----------------
// Q: [b][h][s][d] bf16 (pre-scaled by 0.125), K: [b][kvh][s][d], V: [b][kvh][d][s]
// O: [b][s][h*HD+d] bf16
__global__ void __launch_bounds__(256)
attn_fwd_kernel(const short* __restrict__ Q, const short* __restrict__ K,
                const short* __restrict__ V, short* __restrict__ O) {
  __shared__ __align__(16) short Ks[4096];  // [64 keys][64 dims], xor-swizzled
  __shared__ __align__(16) short Vs[4096];  // [64 dims][64 keys], xor-swizzled
  const int tid = threadIdx.x;
  const int w = tid >> 6, l = tid & 63;
  const int lg = l >> 4, lr = l & 15;
  const int qblk = blockIdx.x;
  const int h = blockIdx.y;
  const int b = blockIdx.z;
  const int kvh = h >> 2;
  const int q0 = qblk * 64;
  const int qrow = q0 + w * 16 + lr;  // this lane's q column (swapped layout)

  const short* qptr = Q + ((size_t)(b * NH + h) * SEQ + qrow) * HD;
  short8 qf0 = *(const short8*)(qptr + (lg << 3));
  short8 qf1 = *(const short8*)(qptr + 32 + (lg << 3));

  const short* kbase = K + (size_t)(b * NKV + kvh) * SEQ * HD;
  const short* vbase = V + (size_t)(b * NKV + kvh) * HD * SEQ;

  const int c0 = tid, c1 = tid + 256;
  const int r0 = c0 >> 3, e0 = ((c0 & 7) ^ (r0 & 7)) << 3;
  const int r1 = c1 >> 3, e1 = ((c1 & 7) ^ (r1 & 7)) << 3;
  short* lK0 = Ks + w * 512; short* lK1 = Ks + 2048 + w * 512;
  short* lV0 = Vs + w * 512; short* lV1 = Vs + 2048 + w * 512;

  float m_run = -__builtin_inff(), l_run = 0.f;
  f32x4 oacc[4] = {};

  for (int t = 0; t <= qblk; ++t) {
    const int kv0 = t * 64;
    GLD16(kbase + (size_t)(kv0 + r0) * HD + e0, lK0);
    GLD16(kbase + (size_t)(kv0 + r1) * HD + e1, lK1);
    GLD16(vbase + (size_t)r0 * SEQ + kv0 + e0, lV0);
    GLD16(vbase + (size_t)r1 * SEQ + kv0 + e1, lV1);
    __syncthreads();

    // S = K * Q  -> lane holds S[key = kv0+16*t4+4*lg+i][q = qrow]
    f32x4 sacc[4];
#pragma unroll
    for (int t4 = 0; t4 < 4; ++t4) {
      f32x4 z = {};
      int row = t4 * 16 + lr;
      int rx = row & 7;
      short8 a0 = *(const short8*)&Ks[row * 64 + ((lg ^ rx) << 3)];
      short8 a1 = *(const short8*)&Ks[row * 64 + (((4 + lg) ^ rx) << 3)];
      z = __builtin_amdgcn_mfma_f32_16x16x32_bf16(a0, qf0, z, 0, 0, 0);
      z = __builtin_amdgcn_mfma_f32_16x16x32_bf16(a1, qf1, z, 0, 0, 0);
      sacc[t4] = z;
    }

    if (t == qblk) {  // diagonal tile: causal mask
#pragma unroll
      for (int t4 = 0; t4 < 4; ++t4)
#pragma unroll
        for (int i = 0; i < 4; ++i)
          if (kv0 + t4 * 16 + lg * 4 + i > qrow) sacc[t4][i] = -__builtin_inff();
    }

    // online softmax along keys (per q-column = per lane, + 4-group reduce)
    float tm = -__builtin_inff();
#pragma unroll
    for (int t4 = 0; t4 < 4; ++t4)
#pragma unroll
      for (int i = 0; i < 4; ++i) tm = fmaxf(tm, sacc[t4][i]);
    tm = fmaxf(tm, __shfl_xor(tm, 16));
    tm = fmaxf(tm, __shfl_xor(tm, 32));
    float m_new = fmaxf(m_run, tm);
    float alpha = __expf(m_run - m_new);
    float p[16];
    float lsum = 0.f;
#pragma unroll
    for (int t4 = 0; t4 < 4; ++t4)
#pragma unroll
      for (int i = 0; i < 4; ++i) {
        float e = __expf(sacc[t4][i] - m_new);
        p[t4 * 4 + i] = e;
        lsum += e;
      }
    lsum += __shfl_xor(lsum, 16);
    lsum += __shfl_xor(lsum, 32);
    l_run = l_run * alpha + lsum;
    m_run = m_new;

    // rescale O (O rows are q = lg*4+i; alpha lives at lane (q) in [0,16))
    float av0 = __shfl(alpha, (lg << 2));
    float av1 = __shfl(alpha, (lg << 2) | 1);
    float av2 = __shfl(alpha, (lg << 2) | 2);
    float av3 = __shfl(alpha, (lg << 2) | 3);
#pragma unroll
    for (int nt = 0; nt < 4; ++nt) {
      oacc[nt][0] *= av0; oacc[nt][1] *= av1;
      oacc[nt][2] *= av2; oacc[nt][3] *= av3;
    }

    // P fragments: k-bijection chosen so swapped-S regs feed PV A directly
    short8 pa0, pa1;
#pragma unroll
    for (int i = 0; i < 4; ++i) {
      pa0[i] = f2bf(p[i]);          // keys 4*lg+i        (tile 0)
      pa0[i + 4] = f2bf(p[4 + i]);  // keys 16+4*lg+i     (tile 1)
      pa1[i] = f2bf(p[8 + i]);      // keys 32+4*lg+i     (tile 2)
      pa1[i + 4] = f2bf(p[12 + i]); // keys 48+4*lg+i     (tile 3)
    }

    // O += P * V   (B = V^T tile, same k-bijection)
    const int lh = lg >> 1, sub = (lg & 1) << 2;
#pragma unroll
    for (int nt = 0; nt < 4; ++nt) {
      int row = nt * 16 + lr;  // dim row
      int rx = row & 7;
#pragma unroll
      for (int ks = 0; ks < 2; ++ks) {
        short4v v0 = *(const short4v*)&Vs[row * 64 + (((4 * ks + lh) ^ rx) << 3) + sub];
        short4v v1 = *(const short4v*)&Vs[row * 64 + (((4 * ks + 2 + lh) ^ rx) << 3) + sub];
        short8 vb;
        vb[0] = v0.x; vb[1] = v0.y; vb[2] = v0.z; vb[3] = v0.w;
        vb[4] = v1.x; vb[5] = v1.y; vb[6] = v1.z; vb[7] = v1.w;
        oacc[nt] = __builtin_amdgcn_mfma_f32_16x16x32_bf16(ks == 0 ? pa0 : pa1, vb, oacc[nt], 0, 0, 0);
      }
    }
    __syncthreads();
  }

  float lv0 = __shfl(l_run, (lg << 2));
  float lv1 = __shfl(l_run, (lg << 2) | 1);
  float lv2 = __shfl(l_run, (lg << 2) | 2);
  float lv3 = __shfl(l_run, (lg << 2) | 3);
  float linv0 = 1.f / lv0, linv1 = 1.f / lv1, linv2 = 1.f / lv2, linv3 = 1.f / lv3;
#pragma unroll
  for (int nt = 0; nt < 4; ++nt) {
    int d = nt * 16 + lr;
    int qb = q0 + w * 16 + lg * 4;
    O[(size_t)(b * SEQ + qb + 0) * DIM + h * HD + d] = f2bf(oacc[nt][0] * linv0);
    O[(size_t)(b * SEQ + qb + 1) * DIM + h * HD + d] = f2bf(oacc[nt][1] * linv1);
    O[(size_t)(b * SEQ + qb + 2) * DIM + h * HD + d] = f2bf(oacc[nt][2] * linv2);
    O[(size_t)(b * SEQ + qb + 3) * DIM + h * HD + d] = f2bf(oacc[nt][3] * linv3);
  }
}

// ---------------- launch ----------------

extern "C" void kernel_launch(void* const* d_in, const int* in_sizes, int n_in,
                              void* d_out, int out_size, void* d_ws, size_t ws_size,
                              hipStream_t stream) {
  const float* x  = (const float*)d_in[0];
  const float* wq = (const float*)d_in[1];
  const float* wk = (const float*)d_in[2];
  const float* wv = (const float*)d_in[3];
  const float* wo = (const float*)d_in[4];
  float* out = (float*)d_out;
  char* ws = (char*)d_ws;

  // workspace layout (bytes); attn aliases x_bf (x_bf dead after V-GEMM),
  // wo_t aliases wq_t (wq_t dead after Q-GEMM)
  short* x_bf  = (short*)(ws + 0);          // 16 MB  [4096][2048]
  short* attn  = (short*)(ws + 0);          // alias of x_bf
  short* q_ws  = (short*)(ws + 16777216);   // 16 MB  [b][h][s][d]
  short* k_ws  = (short*)(ws + 33554432);   // 4 MB   [b][kvh][s][d]
  short* v_ws  = (short*)(ws + 37748736);   // 4 MB   [b][kvh][d][s]
  short* wq_t  = (short*)(ws + 41943040);   // 8 MB   [N][K]
  short* wo_t  = (short*)(ws + 41943040);   // alias of wq_t
  short* wk_t  = (short*)(ws + 50331648);   // 2 MB
  short* wv_t  = (short*)(ws + 52428800);   // 2 MB
  float* ct    = (float*)(ws + 54525952);   // 256 KB
  float* st    = (float*)(ws + 54788096);   // 256 KB
  (void)ws_size; (void)in_sizes; (void)n_in; (void)out_size;

  dim3 tb(32, 8);
  cvt_x_kernel<<<8192, 256, 0, stream>>>(x, x_bf, 2097152);
  transpose_bf_kernel<<<dim3(64, 64), tb, 0, stream>>>(wq, wq_t, DIM, 2048);
  transpose_bf_kernel<<<dim3(16, 64), tb, 0, stream>>>(wk, wk_t, DIM, 512);
  transpose_bf_kernel<<<dim3(16, 64), tb, 0, stream>>>(wv, wv_t, DIM, 512);
  rope_tab_kernel<<<256, 256, 0, stream>>>(ct, st);

  gemm_bf_kernel<1><<<dim3(16, 32), 256, 0, stream>>>(x_bf, wq_t, q_ws, ct, st);
  gemm_bf_kernel<2><<<dim3(4, 32), 256, 0, stream>>>(x_bf, wk_t, k_ws, ct, st);
  gemm_bf_kernel<3><<<dim3(4, 32), 256, 0, stream>>>(x_bf, wv_t, v_ws, ct, st);

  attn_fwd_kernel<<<dim3(32, 32, 2), 256, 0, stream>>>(q_ws, k_ws, v_ws, attn);

  transpose_bf_kernel<<<dim3(64, 64), tb, 0, stream>>>(wo, wo_t, DIM, 2048);
  gemm_bf_kernel<0><<<dim3(16, 32), 256, 0, stream>>>(attn, wo_t, out, ct, st);
}

// Round 2
// 286.902 us; speedup vs baseline: 1.2523x; 1.2523x over previous
//
#include <hip/hip_runtime.h>
#include <stdint.h>

#define DIM   2048
#define NH    32
#define NKV   8
#define HD    64
#define BATCH 2
#define SEQ   2048

typedef __attribute__((ext_vector_type(8))) short  short8;
typedef __attribute__((ext_vector_type(4))) short  short4v;
typedef __attribute__((ext_vector_type(4))) float  f32x4;

#if __has_builtin(__builtin_amdgcn_exp2f)
#define EXP2(x) __builtin_amdgcn_exp2f(x)
#else
#define EXP2(x) exp2f(x)
#endif

static __device__ __forceinline__ short f2bf(float f) {
  union { float f; uint32_t u; } v; v.f = f;
  uint32_t r = v.u + 0x7FFFu + ((v.u >> 16) & 1u);
  return (short)(r >> 16);
}

static __device__ __forceinline__ uint32_t cvtpk_bf16(float lo, float hi) {
  uint32_t r;
  asm("v_cvt_pk_bf16_f32 %0, %1, %2" : "=v"(r) : "v"(lo), "v"(hi));
  return r;
}

#define GLD16(gp, lp) __builtin_amdgcn_global_load_lds(                      \
    (__attribute__((address_space(1))) void*)(void*)(gp),                    \
    (__attribute__((address_space(3))) void*)(lp), 16, 0, 0)

// log2(e) * (1/sqrt(HD))  folded into Q at projection time
#define QSCALE 0.1803368801111244f

// ---------------- prep kernels ----------------

__global__ void cvt_x_kernel(const float* __restrict__ in, short* __restrict__ out, int n4) {
  int i = blockIdx.x * blockDim.x + threadIdx.x;
  if (i < n4) {
    f32x4 v = *reinterpret_cast<const f32x4*>(in + (size_t)i * 4);
    short4v o;
    o.x = f2bf(v.x); o.y = f2bf(v.y); o.z = f2bf(v.z); o.w = f2bf(v.w);
    *reinterpret_cast<short4v*>(out + (size_t)i * 4) = o;
  }
}

// in: [R][C] f32  ->  out: [C][R] bf16
__global__ void transpose_bf_kernel(const float* __restrict__ in, short* __restrict__ out,
                                    int R, int C) {
  __shared__ float t[32][33];
  int c0 = blockIdx.x * 32, r0 = blockIdx.y * 32;
  int tx = threadIdx.x, ty = threadIdx.y;  // (32, 8)
#pragma unroll
  for (int j = 0; j < 32; j += 8)
    t[ty + j][tx] = in[(size_t)(r0 + ty + j) * C + c0 + tx];
  __syncthreads();
#pragma unroll
  for (int j = 0; j < 32; j += 8)
    out[(size_t)(c0 + ty + j) * R + r0 + tx] = f2bf(t[tx][ty + j]);
}

__global__ void rope_tab_kernel(float* __restrict__ ct, float* __restrict__ st) {
  int i = blockIdx.x * blockDim.x + threadIdx.x;  // SEQ*32
  if (i < SEQ * 32) {
    int pos = i >> 5, f = i & 31;
    float inv = powf(10000.0f, -(float)f / 32.0f);
    float th = (float)pos * inv;
    ct[i] = cosf(th);
    st[i] = sinf(th);
  }
}

// ---------------- shared GEMM mainloop: 128x128 tile, BK=32, 2-phase dbuf ----------------
// As/Bs are [2][4096] shorts ([128][32] per buffer); acc = 4x4 f32x4 per wave.
__device__ __forceinline__ void gemm_mainloop(const short* __restrict__ A,
                                              const short* __restrict__ Bt,
                                              int m0, int n0,
                                              short* As, short* Bs,
                                              f32x4 (&acc)[4][4]) {
  const int tid = threadIdx.x;
  const int w = tid >> 6, l = tid & 63;
  const int lg = l >> 4, lr = l & 15;
  const int wr = w >> 1, wc = w & 1;
  const int cA1 = tid + 256;
  const int rA0 = tid >> 2, kA0 = ((tid & 3) ^ (rA0 & 3)) << 3;
  const int rA1 = cA1 >> 2, kA1 = ((cA1 & 3) ^ (rA1 & 3)) << 3;
  const short* gA0 = A + (size_t)(m0 + rA0) * DIM + kA0;
  const short* gA1 = A + (size_t)(m0 + rA1) * DIM + kA1;
  const short* gB0 = Bt + (size_t)(n0 + rA0) * DIM + kA0;
  const short* gB1 = Bt + (size_t)(n0 + rA1) * DIM + kA1;

  // prologue: stage k0=0 into buffer 0
  GLD16(gA0, As + w * 512);
  GLD16(gA1, As + 2048 + w * 512);
  GLD16(gB0, Bs + w * 512);
  GLD16(gB1, Bs + 2048 + w * 512);
  __syncthreads();

  int cur = 0;
  for (int k0 = 0; k0 < DIM; k0 += 32) {
    if (k0 + 32 < DIM) {  // stage next tile into other buffer (overlaps compute)
      const int nx = (cur ^ 1) * 4096;
      GLD16(gA0 + k0 + 32, As + nx + w * 512);
      GLD16(gA1 + k0 + 32, As + nx + 2048 + w * 512);
      GLD16(gB0 + k0 + 32, Bs + nx + w * 512);
      GLD16(gB1 + k0 + 32, Bs + nx + 2048 + w * 512);
    }
    const short* as_ = As + cur * 4096;
    const short* bs_ = Bs + cur * 4096;
    short8 af[4], bq[4];
#pragma unroll
    for (int mt = 0; mt < 4; ++mt) {
      int row = wr * 64 + mt * 16 + lr;
      af[mt] = *(const short8*)&as_[row * 32 + ((lg ^ (row & 3)) << 3)];
    }
#pragma unroll
    for (int nt = 0; nt < 4; ++nt) {
      int row = wc * 64 + nt * 16 + lr;
      bq[nt] = *(const short8*)&bs_[row * 32 + ((lg ^ (row & 3)) << 3)];
    }
#pragma unroll
    for (int mt = 0; mt < 4; ++mt)
#pragma unroll
      for (int nt = 0; nt < 4; ++nt)
        acc[mt][nt] = __builtin_amdgcn_mfma_f32_16x16x32_bf16(af[mt], bq[nt], acc[mt][nt], 0, 0, 0);
    __syncthreads();  // drains vmcnt(0): next buffer staged, this buffer's reads done
    cur ^= 1;
  }
}

// ---------------- fused QKV projection ----------------
// grid.x = 24 tiles of 128 cols over [wq | wk | wv] (2048 + 512 + 512)
// MODE 1: RoPE * QSCALE -> q_ws[b][h][s][d];  MODE 2: RoPE -> k_ws[b][kvh][s][d]
// MODE 3: plain -> v_ws[b][kvh][d][s] (transposed)
__global__ void __launch_bounds__(256)
gemm_qkv_kernel(const short* __restrict__ A,
                const short* __restrict__ wqt, const short* __restrict__ wkt,
                const short* __restrict__ wvt,
                short* __restrict__ q_ws, short* __restrict__ k_ws, short* __restrict__ v_ws,
                const float* __restrict__ ct, const float* __restrict__ st) {
  __shared__ __align__(16) short As[8192];
  __shared__ __align__(16) short Bs[8192];
  const int n0g = blockIdx.x * 128;
  int mode, n0;
  const short* Bt;
  short* outp;
  if (n0g < 2048)      { mode = 1; Bt = wqt; n0 = n0g;        outp = q_ws; }
  else if (n0g < 2560) { mode = 2; Bt = wkt; n0 = n0g - 2048; outp = k_ws; }
  else                 { mode = 3; Bt = wvt; n0 = n0g - 2560; outp = v_ws; }
  const int m0 = blockIdx.y * 128;

  f32x4 acc[4][4] = {};
  gemm_mainloop(A, Bt, m0, n0, As, Bs, acc);

  const int tid = threadIdx.x;
  const int w = tid >> 6, l = tid & 63;
  const int lg = l >> 4, lr = l & 15;
  const int wr = w >> 1, wc = w & 1;
  const int mrow0 = m0 + wr * 64;
  const int ncol0 = n0 + wc * 64;
#pragma unroll
  for (int mt = 0; mt < 4; ++mt)
#pragma unroll
    for (int nt = 0; nt < 4; ++nt)
#pragma unroll
      for (int i = 0; i < 4; ++i) {
        int m = mrow0 + mt * 16 + lg * 4 + i;
        int n = ncol0 + nt * 16 + lr;
        float v = acc[mt][nt][i];
        int b = m >> 11, s = m & (SEQ - 1);
        int h = n >> 6, d = n & 63;
        if (mode == 3) {
          outp[((size_t)(b * NKV + h) * HD + d) * SEQ + s] = f2bf(v);
        } else {
          float p = __shfl_xor(v, 1);
          float cs = ct[(s << 5) + (d >> 1)];
          float sn = st[(s << 5) + (d >> 1)];
          float r = ((d & 1) == 0) ? (v * cs - p * sn) : (p * sn + v * cs);
          if (mode == 1) {
            r *= QSCALE;  // 1/sqrt(HD) * log2(e): softmax done in exp2 domain
            outp[((size_t)(b * NH + h) * SEQ + s) * HD + d] = f2bf(r);
          } else {
            outp[((size_t)(b * NKV + h) * SEQ + s) * HD + d] = f2bf(r);
          }
        }
      }
}

// ---------------- O projection (f32 out) ----------------
__global__ void __launch_bounds__(256)
gemm_o_kernel(const short* __restrict__ A, const short* __restrict__ Bt,
              float* __restrict__ out) {
  __shared__ __align__(16) short As[8192];
  __shared__ __align__(16) short Bs[8192];
  const int m0 = blockIdx.y * 128, n0 = blockIdx.x * 128;
  f32x4 acc[4][4] = {};
  gemm_mainloop(A, Bt, m0, n0, As, Bs, acc);
  const int tid = threadIdx.x;
  const int w = tid >> 6, l = tid & 63;
  const int lg = l >> 4, lr = l & 15;
  const int wr = w >> 1, wc = w & 1;
#pragma unroll
  for (int mt = 0; mt < 4; ++mt)
#pragma unroll
    for (int nt = 0; nt < 4; ++nt)
#pragma unroll
      for (int i = 0; i < 4; ++i) {
        int m = m0 + wr * 64 + mt * 16 + lg * 4 + i;
        int n = n0 + wc * 64 + nt * 16 + lr;
        out[(size_t)m * DIM + n] = acc[mt][nt][i];
      }
}

// ---------------- flash attention (swapped QK^T, GQA, causal, exp2 domain) ----------------
// Q: [b][h][s][d] bf16 (pre-scaled by QSCALE), K: [b][kvh][s][d], V: [b][kvh][d][s]
// O: [b][s][h*HD+d] bf16
// Each block processes q-tiles {x, 31-x} -> uniform 33 KV tiles per block.
__global__ void __launch_bounds__(256)
attn_fwd_kernel(const short* __restrict__ Q, const short* __restrict__ K,
                const short* __restrict__ V, short* __restrict__ O) {
  __shared__ __align__(16) short Ks[2][4096];  // [64 keys][64 dims], xor-swizzled
  __shared__ __align__(16) short Vs[2][4096];  // [64 dims][64 keys], xor-swizzled
  const int tid = threadIdx.x;
  const int w = tid >> 6, l = tid & 63;
  const int lg = l >> 4, lr = l & 15;
  const int h = blockIdx.y;
  const int b = blockIdx.z;
  const int kvh = h >> 2;

  const short* kbase = K + (size_t)(b * NKV + kvh) * SEQ * HD;
  const short* vbase = V + (size_t)(b * NKV + kvh) * HD * SEQ;

  const int c1 = tid + 256;
  const int r0 = tid >> 3, e0 = ((tid & 7) ^ (r0 & 7)) << 3;
  const int r1 = c1 >> 3, e1 = ((c1 & 7) ^ (r1 & 7)) << 3;

  for (int qi = 0; qi < 2; ++qi) {
    const int qblk = (qi == 0) ? (int)blockIdx.x : (31 - (int)blockIdx.x);
    const int q0 = qblk * 64;
    const int qrow = q0 + w * 16 + lr;  // this lane's q column (swapped layout)

    const short* qptr = Q + ((size_t)(b * NH + h) * SEQ + qrow) * HD;
    short8 qf0 = *(const short8*)(qptr + (lg << 3));
    short8 qf1 = *(const short8*)(qptr + 32 + (lg << 3));

    float m_run = -__builtin_inff(), l_run = 0.f;
    f32x4 oacc[4] = {};

    // prologue: stage KV tile 0 into buffer 0
    GLD16(kbase + (size_t)r0 * HD + e0, &Ks[0][w * 512]);
    GLD16(kbase + (size_t)r1 * HD + e1, &Ks[0][2048 + w * 512]);
    GLD16(vbase + (size_t)r0 * SEQ + e0, &Vs[0][w * 512]);
    GLD16(vbase + (size_t)r1 * SEQ + e1, &Vs[0][2048 + w * 512]);
    __syncthreads();

    int cur = 0;
    for (int t = 0; t <= qblk; ++t) {
      const int kv0 = t * 64;
      if (t < qblk) {  // stage next tile (overlaps with compute below)
        const int kv1 = kv0 + 64;
        const int nx = cur ^ 1;
        GLD16(kbase + (size_t)(kv1 + r0) * HD + e0, &Ks[nx][w * 512]);
        GLD16(kbase + (size_t)(kv1 + r1) * HD + e1, &Ks[nx][2048 + w * 512]);
        GLD16(vbase + (size_t)r0 * SEQ + kv1 + e0, &Vs[nx][w * 512]);
        GLD16(vbase + (size_t)r1 * SEQ + kv1 + e1, &Vs[nx][2048 + w * 512]);
      }
      const short* ks = Ks[cur];
      const short* vs = Vs[cur];

      // S = K * Q  -> lane holds S[key = kv0+16*t4+4*lg+i][q = qrow] (log2-scaled)
      f32x4 sacc[4];
#pragma unroll
      for (int t4 = 0; t4 < 4; ++t4) {
        f32x4 z = {};
        int row = t4 * 16 + lr;
        int rx = row & 7;
        short8 a0 = *(const short8*)&ks[row * 64 + ((lg ^ rx) << 3)];
        short8 a1 = *(const short8*)&ks[row * 64 + (((4 + lg) ^ rx) << 3)];
        z = __builtin_amdgcn_mfma_f32_16x16x32_bf16(a0, qf0, z, 0, 0, 0);
        z = __builtin_amdgcn_mfma_f32_16x16x32_bf16(a1, qf1, z, 0, 0, 0);
        sacc[t4] = z;
      }

      if (t == qblk) {  // diagonal tile: causal mask
#pragma unroll
        for (int t4 = 0; t4 < 4; ++t4)
#pragma unroll
          for (int i = 0; i < 4; ++i)
            if (kv0 + t4 * 16 + lg * 4 + i > qrow) sacc[t4][i] = -__builtin_inff();
      }

      // tile max (per q-column = per lane, then across the 4 lg lanes)
      float tm = fmaxf(fmaxf(fmaxf(sacc[0][0], sacc[0][1]), fmaxf(sacc[0][2], sacc[0][3])),
                       fmaxf(fmaxf(sacc[1][0], sacc[1][1]), fmaxf(sacc[1][2], sacc[1][3])));
      float tm2 = fmaxf(fmaxf(fmaxf(sacc[2][0], sacc[2][1]), fmaxf(sacc[2][2], sacc[2][3])),
                        fmaxf(fmaxf(sacc[3][0], sacc[3][1]), fmaxf(sacc[3][2], sacc[3][3])));
      tm = fmaxf(tm, tm2);
      tm = fmaxf(tm, __shfl_xor(tm, 16));
      tm = fmaxf(tm, __shfl_xor(tm, 32));

      // defer-max: only rescale when the max grew past THR (log2 domain; P <= 2^12)
      if (!__all(tm <= m_run + 12.0f)) {
        float m_new = fmaxf(m_run, tm);
        float alpha = EXP2(m_run - m_new);
        float av0 = __shfl(alpha, (lg << 2));
        float av1 = __shfl(alpha, (lg << 2) | 1);
        float av2 = __shfl(alpha, (lg << 2) | 2);
        float av3 = __shfl(alpha, (lg << 2) | 3);
#pragma unroll
        for (int nt = 0; nt < 4; ++nt) {
          oacc[nt][0] *= av0; oacc[nt][1] *= av1;
          oacc[nt][2] *= av2; oacc[nt][3] *= av3;
        }
        l_run *= alpha;
        m_run = m_new;
      }

      // P = exp2(S - m_run); row-sum
      float p[16];
      float lsum = 0.f;
#pragma unroll
      for (int t4 = 0; t4 < 4; ++t4)
#pragma unroll
        for (int i = 0; i < 4; ++i) {
          float e = EXP2(sacc[t4][i] - m_run);
          p[t4 * 4 + i] = e;
          lsum += e;
        }
      lsum += __shfl_xor(lsum, 16);
      lsum += __shfl_xor(lsum, 32);
      l_run += lsum;

      // pack P -> bf16 fragments (k-bijection feeds PV A directly)
      union { short8 s8; uint32_t u[4]; } pa0, pa1;
      pa0.u[0] = cvtpk_bf16(p[0], p[1]);
      pa0.u[1] = cvtpk_bf16(p[2], p[3]);
      pa0.u[2] = cvtpk_bf16(p[4], p[5]);
      pa0.u[3] = cvtpk_bf16(p[6], p[7]);
      pa1.u[0] = cvtpk_bf16(p[8], p[9]);
      pa1.u[1] = cvtpk_bf16(p[10], p[11]);
      pa1.u[2] = cvtpk_bf16(p[12], p[13]);
      pa1.u[3] = cvtpk_bf16(p[14], p[15]);

      // O += P * V   (B = V^T tile, same k-bijection)
      const int lh = lg >> 1, sub = (lg & 1) << 2;
#pragma unroll
      for (int nt = 0; nt < 4; ++nt) {
        int row = nt * 16 + lr;  // dim row
        int rx = row & 7;
#pragma unroll
        for (int ks_ = 0; ks_ < 2; ++ks_) {
          union { short8 s8; short4v h[2]; } vb;
          vb.h[0] = *(const short4v*)&vs[row * 64 + (((4 * ks_ + lh) ^ rx) << 3) + sub];
          vb.h[1] = *(const short4v*)&vs[row * 64 + (((4 * ks_ + 2 + lh) ^ rx) << 3) + sub];
          oacc[nt] = __builtin_amdgcn_mfma_f32_16x16x32_bf16(ks_ == 0 ? pa0.s8 : pa1.s8, vb.s8,
                                                             oacc[nt], 0, 0, 0);
        }
      }
      __syncthreads();
      cur ^= 1;
    }

    // epilogue: normalize and store
    float lv0 = __shfl(l_run, (lg << 2));
    float lv1 = __shfl(l_run, (lg << 2) | 1);
    float lv2 = __shfl(l_run, (lg << 2) | 2);
    float lv3 = __shfl(l_run, (lg << 2) | 3);
    float linv0 = 1.f / lv0, linv1 = 1.f / lv1, linv2 = 1.f / lv2, linv3 = 1.f / lv3;
#pragma unroll
    for (int nt = 0; nt < 4; ++nt) {
      int d = nt * 16 + lr;
      int qb = q0 + w * 16 + lg * 4;
      O[(size_t)(b * SEQ + qb + 0) * DIM + h * HD + d] = f2bf(oacc[nt][0] * linv0);
      O[(size_t)(b * SEQ + qb + 1) * DIM + h * HD + d] = f2bf(oacc[nt][1] * linv1);
      O[(size_t)(b * SEQ + qb + 2) * DIM + h * HD + d] = f2bf(oacc[nt][2] * linv2);
      O[(size_t)(b * SEQ + qb + 3) * DIM + h * HD + d] = f2bf(oacc[nt][3] * linv3);
    }
  }
}

// ---------------- launch ----------------

extern "C" void kernel_launch(void* const* d_in, const int* in_sizes, int n_in,
                              void* d_out, int out_size, void* d_ws, size_t ws_size,
                              hipStream_t stream) {
  const float* x  = (const float*)d_in[0];
  const float* wq = (const float*)d_in[1];
  const float* wk = (const float*)d_in[2];
  const float* wv = (const float*)d_in[3];
  const float* wo = (const float*)d_in[4];
  float* out = (float*)d_out;
  char* ws = (char*)d_ws;

  // workspace layout (bytes); attn aliases x_bf (dead after QKV GEMM),
  // wo_t aliases wq_t (dead after QKV GEMM)
  short* x_bf  = (short*)(ws + 0);          // 16 MB  [4096][2048]
  short* attn  = (short*)(ws + 0);          // alias of x_bf
  short* q_ws  = (short*)(ws + 16777216);   // 16 MB  [b][h][s][d]
  short* k_ws  = (short*)(ws + 33554432);   // 4 MB   [b][kvh][s][d]
  short* v_ws  = (short*)(ws + 37748736);   // 4 MB   [b][kvh][d][s]
  short* wq_t  = (short*)(ws + 41943040);   // 8 MB   [N][K]
  short* wo_t  = (short*)(ws + 41943040);   // alias of wq_t
  short* wk_t  = (short*)(ws + 50331648);   // 2 MB
  short* wv_t  = (short*)(ws + 52428800);   // 2 MB
  float* ct    = (float*)(ws + 54525952);   // 256 KB
  float* st    = (float*)(ws + 54788096);   // 256 KB
  (void)ws_size; (void)in_sizes; (void)n_in; (void)out_size;

  dim3 tb(32, 8);
  cvt_x_kernel<<<8192, 256, 0, stream>>>(x, x_bf, 2097152);
  transpose_bf_kernel<<<dim3(64, 64), tb, 0, stream>>>(wq, wq_t, DIM, 2048);
  transpose_bf_kernel<<<dim3(16, 64), tb, 0, stream>>>(wk, wk_t, DIM, 512);
  transpose_bf_kernel<<<dim3(16, 64), tb, 0, stream>>>(wv, wv_t, DIM, 512);
  rope_tab_kernel<<<256, 256, 0, stream>>>(ct, st);

  gemm_qkv_kernel<<<dim3(24, 32), 256, 0, stream>>>(x_bf, wq_t, wk_t, wv_t,
                                                    q_ws, k_ws, v_ws, ct, st);

  attn_fwd_kernel<<<dim3(16, 32, 2), 256, 0, stream>>>(q_ws, k_ws, v_ws, attn);

  transpose_bf_kernel<<<dim3(64, 64), tb, 0, stream>>>(wo, wo_t, DIM, 2048);
  gemm_o_kernel<<<dim3(16, 32), 256, 0, stream>>>(attn, wo_t, out);
}

// Round 3
// 238.242 us; speedup vs baseline: 1.5081x; 1.2042x over previous
//
#include <hip/hip_runtime.h>
#include <stdint.h>

#define DIM   2048
#define NH    32
#define NKV   8
#define HD    64
#define BATCH 2
#define SEQ   2048

typedef __attribute__((ext_vector_type(8))) short  short8;
typedef __attribute__((ext_vector_type(4))) short  short4v;
typedef __attribute__((ext_vector_type(4))) float  f32x4;

#if __has_builtin(__builtin_amdgcn_exp2f)
#define EXP2(x) __builtin_amdgcn_exp2f(x)
#else
#define EXP2(x) exp2f(x)
#endif

static __device__ __forceinline__ short f2bf(float f) {
  union { float f; uint32_t u; } v; v.f = f;
  uint32_t r = v.u + 0x7FFFu + ((v.u >> 16) & 1u);
  return (short)(r >> 16);
}

static __device__ __forceinline__ uint32_t cvtpk_bf16(float lo, float hi) {
  uint32_t r;
  asm("v_cvt_pk_bf16_f32 %0, %1, %2" : "=v"(r) : "v"(lo), "v"(hi));
  return r;
}

#define GLD16(gp, lp) __builtin_amdgcn_global_load_lds(                      \
    (__attribute__((address_space(1))) void*)(void*)(gp),                    \
    (__attribute__((address_space(3))) void*)(lp), 16, 0, 0)

// log2(e) * (1/sqrt(HD))  folded into Q at projection time
#define QSCALE 0.1803368801111244f

// ---------------- prep kernels ----------------

__global__ void cvt_x_kernel(const float* __restrict__ in, short* __restrict__ out, int n4) {
  int i = blockIdx.x * blockDim.x + threadIdx.x;
  if (i < n4) {
    f32x4 v = *reinterpret_cast<const f32x4*>(in + (size_t)i * 4);
    short4v o;
    o.x = f2bf(v.x); o.y = f2bf(v.y); o.z = f2bf(v.z); o.w = f2bf(v.w);
    *reinterpret_cast<short4v*>(out + (size_t)i * 4) = o;
  }
}

// in: [R][C] f32  ->  out: [C][R] bf16
__global__ void transpose_bf_kernel(const float* __restrict__ in, short* __restrict__ out,
                                    int R, int C) {
  __shared__ float t[32][33];
  int c0 = blockIdx.x * 32, r0 = blockIdx.y * 32;
  int tx = threadIdx.x, ty = threadIdx.y;  // (32, 8)
#pragma unroll
  for (int j = 0; j < 32; j += 8)
    t[ty + j][tx] = in[(size_t)(r0 + ty + j) * C + c0 + tx];
  __syncthreads();
#pragma unroll
  for (int j = 0; j < 32; j += 8)
    out[(size_t)(c0 + ty + j) * R + r0 + tx] = f2bf(t[tx][ty + j]);
}

__global__ void rope_tab_kernel(float* __restrict__ ct, float* __restrict__ st) {
  int i = blockIdx.x * blockDim.x + threadIdx.x;  // SEQ*32
  if (i < SEQ * 32) {
    int pos = i >> 5, f = i & 31;
    float inv = powf(10000.0f, -(float)f / 32.0f);
    float th = (float)pos * inv;
    ct[i] = cosf(th);
    st[i] = sinf(th);
  }
}

// ---------------- pipelined GEMM mainloop ----------------
// 128x128 tile, BK=32, 4 waves (2x2), 3 LDS buffers (48 KB), stage t+2 while
// computing t.  Counted vmcnt: at tile-t start each wave waits vmcnt(4) so its
// own 4 loads for tile t are retired (only tile t+1's 4 remain), then s_barrier
// joins all waves -> tile t fully staged, and all waves' tile t-1 reads done ->
// staging for t+2 (issued after the barrier) cannot overwrite live data.
// Swizzle: 16B-unit ^= (row>>1)&3 (banks wrap every 2 rows at 64B rows) -> 2-way.

__device__ __forceinline__ void mfma_tile(const short* __restrict__ as_,
                                          const short* __restrict__ bs_,
                                          int wr, int wc, int lg, int lr,
                                          f32x4 (&acc)[4][4]) {
  short8 af[4], bq[4];
#pragma unroll
  for (int mt = 0; mt < 4; ++mt) {
    int row = wr * 64 + mt * 16 + lr;
    af[mt] = *(const short8*)&as_[row * 32 + ((lg ^ ((row >> 1) & 3)) << 3)];
  }
#pragma unroll
  for (int nt = 0; nt < 4; ++nt) {
    int row = wc * 64 + nt * 16 + lr;
    bq[nt] = *(const short8*)&bs_[row * 32 + ((lg ^ ((row >> 1) & 3)) << 3)];
  }
  __builtin_amdgcn_s_setprio(1);
#pragma unroll
  for (int mt = 0; mt < 4; ++mt)
#pragma unroll
    for (int nt = 0; nt < 4; ++nt)
      acc[mt][nt] = __builtin_amdgcn_mfma_f32_16x16x32_bf16(af[mt], bq[nt], acc[mt][nt], 0, 0, 0);
  __builtin_amdgcn_s_setprio(0);
}

#define STAGE4(SA, SB) do {                                                  \
    GLD16(pA0, (SA) + w * 512);  GLD16(pA1, (SA) + 2048 + w * 512);          \
    GLD16(pB0, (SB) + w * 512);  GLD16(pB1, (SB) + 2048 + w * 512);          \
    pA0 += 32; pA1 += 32; pB0 += 32; pB1 += 32; } while (0)

#define TILE(CA, CB, SA, SB, DOSTAGE, VM) do {                               \
    asm volatile("s_waitcnt vmcnt(" VM ")" ::: "memory");                    \
    __builtin_amdgcn_s_barrier();                                            \
    __builtin_amdgcn_sched_barrier(0);                                       \
    if (DOSTAGE) { STAGE4(SA, SB); }                                         \
    mfma_tile(CA, CB, wr, wc, lg, lr, acc);                                  \
  } while (0)

// As/Bs: 3 buffers of 4096 shorts each (8 KB per buffer per operand)
__device__ __forceinline__ void gemm_mainloop(const short* __restrict__ A,
                                              const short* __restrict__ Bt,
                                              int m0, int n0,
                                              short* As, short* Bs,
                                              f32x4 (&acc)[4][4]) {
  const int tid = threadIdx.x;
  const int w = tid >> 6, l = tid & 63;
  const int lg = l >> 4, lr = l & 15;
  const int wr = w >> 1, wc = w & 1;
  // staging map: chunk c -> row=c>>2, 16B-unit u=c&3; source unit pre-swizzled
  const int c1 = tid + 256;
  const int r0 = tid >> 2, k0 = ((tid & 3) ^ ((r0 >> 1) & 3)) << 3;
  const int r1 = c1 >> 2,  k1 = ((c1 & 3) ^ ((r1 >> 1) & 3)) << 3;
  const short* pA0 = A + (size_t)(m0 + r0) * DIM + k0;
  const short* pA1 = A + (size_t)(m0 + r1) * DIM + k1;
  const short* pB0 = Bt + (size_t)(n0 + r0) * DIM + k0;
  const short* pB1 = Bt + (size_t)(n0 + r1) * DIM + k1;
  short* A0 = As;            short* B0 = Bs;
  short* A1 = As + 4096;     short* B1 = Bs + 4096;
  short* A2 = As + 8192;     short* B2 = Bs + 8192;

  // prologue: stage tiles 0 and 1
  STAGE4(A0, B0);
  STAGE4(A1, B1);

  // 64 K-tiles total: 20x3 main + 4 peeled
  for (int it = 0; it < 20; ++it) {
    TILE(A0, B0, A2, B2, true, "4");
    TILE(A1, B1, A0, B0, true, "4");
    TILE(A2, B2, A1, B1, true, "4");
  }
  TILE(A0, B0, A2, B2, true,  "4");  // t=60, stage t=62
  TILE(A1, B1, A0, B0, true,  "4");  // t=61, stage t=63
  TILE(A2, B2, A0, B0, false, "4");  // t=62
  TILE(A0, B0, A1, B1, false, "0");  // t=63
}

__device__ __forceinline__ int2 xcd_swizzle(int nwg) {
  int id = blockIdx.y * gridDim.x + blockIdx.x;
  int swz = (id & 7) * (nwg >> 3) + (id >> 3);
  return make_int2(swz % gridDim.x, swz / gridDim.x);
}

// ---------------- fused QKV projection ----------------
__global__ void __launch_bounds__(256, 3)
gemm_qkv_kernel(const short* __restrict__ A,
                const short* __restrict__ wqt, const short* __restrict__ wkt,
                const short* __restrict__ wvt,
                short* __restrict__ q_ws, short* __restrict__ k_ws, short* __restrict__ v_ws,
                const float* __restrict__ ct, const float* __restrict__ st) {
  __shared__ __align__(16) short As[12288];
  __shared__ __align__(16) short Bs[12288];
  int2 bxy = xcd_swizzle(24 * 32);
  const int n0g = bxy.x * 128;
  const int m0 = bxy.y * 128;
  int mode, n0;
  const short* Bt;
  short* outp;
  if (n0g < 2048)      { mode = 1; Bt = wqt; n0 = n0g;        outp = q_ws; }
  else if (n0g < 2560) { mode = 2; Bt = wkt; n0 = n0g - 2048; outp = k_ws; }
  else                 { mode = 3; Bt = wvt; n0 = n0g - 2560; outp = v_ws; }

  f32x4 acc[4][4] = {};
  gemm_mainloop(A, Bt, m0, n0, As, Bs, acc);

  const int tid = threadIdx.x;
  const int w = tid >> 6, l = tid & 63;
  const int lg = l >> 4, lr = l & 15;
  const int wr = w >> 1, wc = w & 1;
  const int mrow0 = m0 + wr * 64;
  const int ncol0 = n0 + wc * 64;
#pragma unroll
  for (int mt = 0; mt < 4; ++mt)
#pragma unroll
    for (int nt = 0; nt < 4; ++nt)
#pragma unroll
      for (int i = 0; i < 4; ++i) {
        int m = mrow0 + mt * 16 + lg * 4 + i;
        int n = ncol0 + nt * 16 + lr;
        float v = acc[mt][nt][i];
        int b = m >> 11, s = m & (SEQ - 1);
        int h = n >> 6, d = n & 63;
        if (mode == 3) {
          outp[((size_t)(b * NKV + h) * HD + d) * SEQ + s] = f2bf(v);
        } else {
          float p = __shfl_xor(v, 1);
          float cs = ct[(s << 5) + (d >> 1)];
          float sn = st[(s << 5) + (d >> 1)];
          float r = ((d & 1) == 0) ? (v * cs - p * sn) : (p * sn + v * cs);
          if (mode == 1) {
            r *= QSCALE;  // 1/sqrt(HD) * log2(e): softmax done in exp2 domain
            outp[((size_t)(b * NH + h) * SEQ + s) * HD + d] = f2bf(r);
          } else {
            outp[((size_t)(b * NKV + h) * SEQ + s) * HD + d] = f2bf(r);
          }
        }
      }
}

// ---------------- O projection (f32 out) ----------------
__global__ void __launch_bounds__(256, 3)
gemm_o_kernel(const short* __restrict__ A, const short* __restrict__ Bt,
              float* __restrict__ out) {
  __shared__ __align__(16) short As[12288];
  __shared__ __align__(16) short Bs[12288];
  int2 bxy = xcd_swizzle(16 * 32);
  const int m0 = bxy.y * 128, n0 = bxy.x * 128;
  f32x4 acc[4][4] = {};
  gemm_mainloop(A, Bt, m0, n0, As, Bs, acc);
  const int tid = threadIdx.x;
  const int w = tid >> 6, l = tid & 63;
  const int lg = l >> 4, lr = l & 15;
  const int wr = w >> 1, wc = w & 1;
#pragma unroll
  for (int mt = 0; mt < 4; ++mt)
#pragma unroll
    for (int nt = 0; nt < 4; ++nt)
#pragma unroll
      for (int i = 0; i < 4; ++i) {
        int m = m0 + wr * 64 + mt * 16 + lg * 4 + i;
        int n = n0 + wc * 64 + nt * 16 + lr;
        out[(size_t)m * DIM + n] = acc[mt][nt][i];
      }
}

// ---------------- flash attention (swapped QK^T, GQA, causal, exp2 domain) ----------------
// Q: [b][h][s][d] bf16 (pre-scaled by QSCALE), K: [b][kvh][s][d], V: [b][kvh][d][s]
// O: [b][s][h*HD+d] bf16
// Each block processes q-tiles {x, 31-x} -> uniform 33 KV tiles per block.
__global__ void __launch_bounds__(256)
attn_fwd_kernel(const short* __restrict__ Q, const short* __restrict__ K,
                const short* __restrict__ V, short* __restrict__ O) {
  __shared__ __align__(16) short Ks[2][4096];  // [64 keys][64 dims], xor-swizzled
  __shared__ __align__(16) short Vs[2][4096];  // [64 dims][64 keys], xor-swizzled
  const int tid = threadIdx.x;
  const int w = tid >> 6, l = tid & 63;
  const int lg = l >> 4, lr = l & 15;
  const int h = blockIdx.y;
  const int b = blockIdx.z;
  const int kvh = h >> 2;

  const short* kbase = K + (size_t)(b * NKV + kvh) * SEQ * HD;
  const short* vbase = V + (size_t)(b * NKV + kvh) * HD * SEQ;

  const int c1 = tid + 256;
  const int r0 = tid >> 3, e0 = ((tid & 7) ^ (r0 & 7)) << 3;
  const int r1 = c1 >> 3, e1 = ((c1 & 7) ^ (r1 & 7)) << 3;

  for (int qi = 0; qi < 2; ++qi) {
    const int qblk = (qi == 0) ? (int)blockIdx.x : (31 - (int)blockIdx.x);
    const int q0 = qblk * 64;
    const int qrow = q0 + w * 16 + lr;  // this lane's q column (swapped layout)

    const short* qptr = Q + ((size_t)(b * NH + h) * SEQ + qrow) * HD;
    short8 qf0 = *(const short8*)(qptr + (lg << 3));
    short8 qf1 = *(const short8*)(qptr + 32 + (lg << 3));

    float m_run = -__builtin_inff(), l_run = 0.f;
    f32x4 oacc[4] = {};

    // prologue: stage KV tile 0 into buffer 0
    GLD16(kbase + (size_t)r0 * HD + e0, &Ks[0][w * 512]);
    GLD16(kbase + (size_t)r1 * HD + e1, &Ks[0][2048 + w * 512]);
    GLD16(vbase + (size_t)r0 * SEQ + e0, &Vs[0][w * 512]);
    GLD16(vbase + (size_t)r1 * SEQ + e1, &Vs[0][2048 + w * 512]);
    __syncthreads();

    int cur = 0;
    for (int t = 0; t <= qblk; ++t) {
      const int kv0 = t * 64;
      if (t < qblk) {  // stage next tile (overlaps with compute below)
        const int kv1 = kv0 + 64;
        const int nx = cur ^ 1;
        GLD16(kbase + (size_t)(kv1 + r0) * HD + e0, &Ks[nx][w * 512]);
        GLD16(kbase + (size_t)(kv1 + r1) * HD + e1, &Ks[nx][2048 + w * 512]);
        GLD16(vbase + (size_t)r0 * SEQ + kv1 + e0, &Vs[nx][w * 512]);
        GLD16(vbase + (size_t)r1 * SEQ + kv1 + e1, &Vs[nx][2048 + w * 512]);
      }
      const short* ks = Ks[cur];
      const short* vs = Vs[cur];

      // S = K * Q  -> lane holds S[key = kv0+16*t4+4*lg+i][q = qrow] (log2-scaled)
      f32x4 sacc[4];
#pragma unroll
      for (int t4 = 0; t4 < 4; ++t4) {
        f32x4 z = {};
        int row = t4 * 16 + lr;
        int rx = row & 7;
        short8 a0 = *(const short8*)&ks[row * 64 + ((lg ^ rx) << 3)];
        short8 a1 = *(const short8*)&ks[row * 64 + (((4 + lg) ^ rx) << 3)];
        z = __builtin_amdgcn_mfma_f32_16x16x32_bf16(a0, qf0, z, 0, 0, 0);
        z = __builtin_amdgcn_mfma_f32_16x16x32_bf16(a1, qf1, z, 0, 0, 0);
        sacc[t4] = z;
      }

      if (t == qblk) {  // diagonal tile: causal mask
#pragma unroll
        for (int t4 = 0; t4 < 4; ++t4)
#pragma unroll
          for (int i = 0; i < 4; ++i)
            if (kv0 + t4 * 16 + lg * 4 + i > qrow) sacc[t4][i] = -__builtin_inff();
      }

      // tile max (per q-column = per lane, then across the 4 lg lanes)
      float tm = fmaxf(fmaxf(fmaxf(sacc[0][0], sacc[0][1]), fmaxf(sacc[0][2], sacc[0][3])),
                       fmaxf(fmaxf(sacc[1][0], sacc[1][1]), fmaxf(sacc[1][2], sacc[1][3])));
      float tm2 = fmaxf(fmaxf(fmaxf(sacc[2][0], sacc[2][1]), fmaxf(sacc[2][2], sacc[2][3])),
                        fmaxf(fmaxf(sacc[3][0], sacc[3][1]), fmaxf(sacc[3][2], sacc[3][3])));
      tm = fmaxf(tm, tm2);
      tm = fmaxf(tm, __shfl_xor(tm, 16));
      tm = fmaxf(tm, __shfl_xor(tm, 32));

      // defer-max: only rescale when the max grew past THR (log2 domain; P <= 2^12)
      if (!__all(tm <= m_run + 12.0f)) {
        float m_new = fmaxf(m_run, tm);
        float alpha = EXP2(m_run - m_new);
        float av0 = __shfl(alpha, (lg << 2));
        float av1 = __shfl(alpha, (lg << 2) | 1);
        float av2 = __shfl(alpha, (lg << 2) | 2);
        float av3 = __shfl(alpha, (lg << 2) | 3);
#pragma unroll
        for (int nt = 0; nt < 4; ++nt) {
          oacc[nt][0] *= av0; oacc[nt][1] *= av1;
          oacc[nt][2] *= av2; oacc[nt][3] *= av3;
        }
        l_run *= alpha;
        m_run = m_new;
      }

      // P = exp2(S - m_run); row-sum
      float p[16];
      float lsum = 0.f;
#pragma unroll
      for (int t4 = 0; t4 < 4; ++t4)
#pragma unroll
        for (int i = 0; i < 4; ++i) {
          float e = EXP2(sacc[t4][i] - m_run);
          p[t4 * 4 + i] = e;
          lsum += e;
        }
      lsum += __shfl_xor(lsum, 16);
      lsum += __shfl_xor(lsum, 32);
      l_run += lsum;

      // pack P -> bf16 fragments (k-bijection feeds PV A directly)
      union { short8 s8; uint32_t u[4]; } pa0, pa1;
      pa0.u[0] = cvtpk_bf16(p[0], p[1]);
      pa0.u[1] = cvtpk_bf16(p[2], p[3]);
      pa0.u[2] = cvtpk_bf16(p[4], p[5]);
      pa0.u[3] = cvtpk_bf16(p[6], p[7]);
      pa1.u[0] = cvtpk_bf16(p[8], p[9]);
      pa1.u[1] = cvtpk_bf16(p[10], p[11]);
      pa1.u[2] = cvtpk_bf16(p[12], p[13]);
      pa1.u[3] = cvtpk_bf16(p[14], p[15]);

      // O += P * V   (B = V^T tile, same k-bijection)
      const int lh = lg >> 1, sub = (lg & 1) << 2;
#pragma unroll
      for (int nt = 0; nt < 4; ++nt) {
        int row = nt * 16 + lr;  // dim row
        int rx = row & 7;
#pragma unroll
        for (int ks_ = 0; ks_ < 2; ++ks_) {
          union { short8 s8; short4v h[2]; } vb;
          vb.h[0] = *(const short4v*)&vs[row * 64 + (((4 * ks_ + lh) ^ rx) << 3) + sub];
          vb.h[1] = *(const short4v*)&vs[row * 64 + (((4 * ks_ + 2 + lh) ^ rx) << 3) + sub];
          oacc[nt] = __builtin_amdgcn_mfma_f32_16x16x32_bf16(ks_ == 0 ? pa0.s8 : pa1.s8, vb.s8,
                                                             oacc[nt], 0, 0, 0);
        }
      }
      __syncthreads();
      cur ^= 1;
    }

    // epilogue: normalize and store
    float lv0 = __shfl(l_run, (lg << 2));
    float lv1 = __shfl(l_run, (lg << 2) | 1);
    float lv2 = __shfl(l_run, (lg << 2) | 2);
    float lv3 = __shfl(l_run, (lg << 2) | 3);
    float linv0 = 1.f / lv0, linv1 = 1.f / lv1, linv2 = 1.f / lv2, linv3 = 1.f / lv3;
#pragma unroll
    for (int nt = 0; nt < 4; ++nt) {
      int d = nt * 16 + lr;
      int qb = q0 + w * 16 + lg * 4;
      O[(size_t)(b * SEQ + qb + 0) * DIM + h * HD + d] = f2bf(oacc[nt][0] * linv0);
      O[(size_t)(b * SEQ + qb + 1) * DIM + h * HD + d] = f2bf(oacc[nt][1] * linv1);
      O[(size_t)(b * SEQ + qb + 2) * DIM + h * HD + d] = f2bf(oacc[nt][2] * linv2);
      O[(size_t)(b * SEQ + qb + 3) * DIM + h * HD + d] = f2bf(oacc[nt][3] * linv3);
    }
  }
}

// ---------------- launch ----------------

extern "C" void kernel_launch(void* const* d_in, const int* in_sizes, int n_in,
                              void* d_out, int out_size, void* d_ws, size_t ws_size,
                              hipStream_t stream) {
  const float* x  = (const float*)d_in[0];
  const float* wq = (const float*)d_in[1];
  const float* wk = (const float*)d_in[2];
  const float* wv = (const float*)d_in[3];
  const float* wo = (const float*)d_in[4];
  float* out = (float*)d_out;
  char* ws = (char*)d_ws;

  // workspace layout (bytes); attn aliases x_bf (dead after QKV GEMM),
  // wo_t aliases wq_t (dead after QKV GEMM)
  short* x_bf  = (short*)(ws + 0);          // 16 MB  [4096][2048]
  short* attn  = (short*)(ws + 0);          // alias of x_bf
  short* q_ws  = (short*)(ws + 16777216);   // 16 MB  [b][h][s][d]
  short* k_ws  = (short*)(ws + 33554432);   // 4 MB   [b][kvh][s][d]
  short* v_ws  = (short*)(ws + 37748736);   // 4 MB   [b][kvh][d][s]
  short* wq_t  = (short*)(ws + 41943040);   // 8 MB   [N][K]
  short* wo_t  = (short*)(ws + 41943040);   // alias of wq_t
  short* wk_t  = (short*)(ws + 50331648);   // 2 MB
  short* wv_t  = (short*)(ws + 52428800);   // 2 MB
  float* ct    = (float*)(ws + 54525952);   // 256 KB
  float* st    = (float*)(ws + 54788096);   // 256 KB
  (void)ws_size; (void)in_sizes; (void)n_in; (void)out_size;

  dim3 tb(32, 8);
  cvt_x_kernel<<<8192, 256, 0, stream>>>(x, x_bf, 2097152);
  transpose_bf_kernel<<<dim3(64, 64), tb, 0, stream>>>(wq, wq_t, DIM, 2048);
  transpose_bf_kernel<<<dim3(16, 64), tb, 0, stream>>>(wk, wk_t, DIM, 512);
  transpose_bf_kernel<<<dim3(16, 64), tb, 0, stream>>>(wv, wv_t, DIM, 512);
  rope_tab_kernel<<<256, 256, 0, stream>>>(ct, st);

  gemm_qkv_kernel<<<dim3(24, 32), 256, 0, stream>>>(x_bf, wq_t, wk_t, wv_t,
                                                    q_ws, k_ws, v_ws, ct, st);

  attn_fwd_kernel<<<dim3(16, 32, 2), 256, 0, stream>>>(q_ws, k_ws, v_ws, attn);

  transpose_bf_kernel<<<dim3(64, 64), tb, 0, stream>>>(wo, wo_t, DIM, 2048);
  gemm_o_kernel<<<dim3(16, 32), 256, 0, stream>>>(attn, wo_t, out);
}

// Round 4
// 221.642 us; speedup vs baseline: 1.6211x; 1.0749x over previous
//
#include <hip/hip_runtime.h>
#include <stdint.h>

#define DIM   2048
#define NH    32
#define NKV   8
#define HD    64
#define BATCH 2
#define SEQ   2048

typedef __attribute__((ext_vector_type(8))) short  short8;
typedef __attribute__((ext_vector_type(4))) short  short4v;
typedef __attribute__((ext_vector_type(4))) float  f32x4;

#if __has_builtin(__builtin_amdgcn_exp2f)
#define EXP2(x) __builtin_amdgcn_exp2f(x)
#else
#define EXP2(x) exp2f(x)
#endif

static __device__ __forceinline__ short f2bf(float f) {
  union { float f; uint32_t u; } v; v.f = f;
  uint32_t r = v.u + 0x7FFFu + ((v.u >> 16) & 1u);
  return (short)(r >> 16);
}

static __device__ __forceinline__ uint32_t cvtpk_bf16(float lo, float hi) {
  uint32_t r;
  asm("v_cvt_pk_bf16_f32 %0, %1, %2" : "=v"(r) : "v"(lo), "v"(hi));
  return r;
}

#define GLD16(gp, lp) __builtin_amdgcn_global_load_lds(                      \
    (__attribute__((address_space(1))) void*)(void*)(gp),                    \
    (__attribute__((address_space(3))) void*)(lp), 16, 0, 0)

// log2(e) * (1/sqrt(HD))  folded into Q at projection time
#define QSCALE 0.1803368801111244f

// ---------------- prep kernels ----------------

__global__ void cvt_x_kernel(const float* __restrict__ in, short* __restrict__ out, int n4) {
  int i = blockIdx.x * blockDim.x + threadIdx.x;
  if (i < n4) {
    f32x4 v = *reinterpret_cast<const f32x4*>(in + (size_t)i * 4);
    short4v o;
    o.x = f2bf(v.x); o.y = f2bf(v.y); o.z = f2bf(v.z); o.w = f2bf(v.w);
    *reinterpret_cast<short4v*>(out + (size_t)i * 4) = o;
  }
}

// in: [R][C] f32  ->  out: [C][R] bf16
__global__ void transpose_bf_kernel(const float* __restrict__ in, short* __restrict__ out,
                                    int R, int C) {
  __shared__ float t[32][33];
  int c0 = blockIdx.x * 32, r0 = blockIdx.y * 32;
  int tx = threadIdx.x, ty = threadIdx.y;  // (32, 8)
#pragma unroll
  for (int j = 0; j < 32; j += 8)
    t[ty + j][tx] = in[(size_t)(r0 + ty + j) * C + c0 + tx];
  __syncthreads();
#pragma unroll
  for (int j = 0; j < 32; j += 8)
    out[(size_t)(c0 + ty + j) * R + r0 + tx] = f2bf(t[tx][ty + j]);
}

__global__ void rope_tab_kernel(float* __restrict__ ct, float* __restrict__ st) {
  int i = blockIdx.x * blockDim.x + threadIdx.x;  // SEQ*32
  if (i < SEQ * 32) {
    int pos = i >> 5, f = i & 31;
    float inv = powf(10000.0f, -(float)f / 32.0f);
    float th = (float)pos * inv;
    ct[i] = cosf(th);
    st[i] = sinf(th);
  }
}

// ---------------- pipelined GEMM mainloop ----------------
// 128x128 tile, BK=32, 4 waves (2x2), 3 LDS buffers (48 KB), stage t+2 while
// computing t.  Counted vmcnt: at tile-t start each wave waits vmcnt(4) so its
// own 4 loads for tile t are retired (only tile t+1's 4 remain), then s_barrier
// joins all waves -> tile t fully staged, and all waves' tile t-1 reads done ->
// staging for t+2 (issued after the barrier) cannot overwrite live data.
// Swizzle: 16B-unit ^= (row>>1)&3 (banks wrap every 2 rows at 64B rows) -> 2-way.

__device__ __forceinline__ void mfma_tile(const short* __restrict__ as_,
                                          const short* __restrict__ bs_,
                                          int wr, int wc, int lg, int lr,
                                          f32x4 (&acc)[4][4]) {
  short8 af[4], bq[4];
#pragma unroll
  for (int mt = 0; mt < 4; ++mt) {
    int row = wr * 64 + mt * 16 + lr;
    af[mt] = *(const short8*)&as_[row * 32 + ((lg ^ ((row >> 1) & 3)) << 3)];
  }
#pragma unroll
  for (int nt = 0; nt < 4; ++nt) {
    int row = wc * 64 + nt * 16 + lr;
    bq[nt] = *(const short8*)&bs_[row * 32 + ((lg ^ ((row >> 1) & 3)) << 3)];
  }
  __builtin_amdgcn_s_setprio(1);
#pragma unroll
  for (int mt = 0; mt < 4; ++mt)
#pragma unroll
    for (int nt = 0; nt < 4; ++nt)
      acc[mt][nt] = __builtin_amdgcn_mfma_f32_16x16x32_bf16(af[mt], bq[nt], acc[mt][nt], 0, 0, 0);
  __builtin_amdgcn_s_setprio(0);
}

#define STAGE4(SA, SB) do {                                                  \
    GLD16(pA0, (SA) + w * 512);  GLD16(pA1, (SA) + 2048 + w * 512);          \
    GLD16(pB0, (SB) + w * 512);  GLD16(pB1, (SB) + 2048 + w * 512);          \
    pA0 += 32; pA1 += 32; pB0 += 32; pB1 += 32; } while (0)

#define TILE(CA, CB, SA, SB, DOSTAGE, VM) do {                               \
    asm volatile("s_waitcnt vmcnt(" VM ")" ::: "memory");                    \
    __builtin_amdgcn_s_barrier();                                            \
    __builtin_amdgcn_sched_barrier(0);                                       \
    if (DOSTAGE) { STAGE4(SA, SB); }                                         \
    mfma_tile(CA, CB, wr, wc, lg, lr, acc);                                  \
  } while (0)

// As/Bs: 3 buffers of 4096 shorts each (8 KB per buffer per operand)
__device__ __forceinline__ void gemm_mainloop(const short* __restrict__ A,
                                              const short* __restrict__ Bt,
                                              int m0, int n0,
                                              short* As, short* Bs,
                                              f32x4 (&acc)[4][4]) {
  const int tid = threadIdx.x;
  const int w = tid >> 6, l = tid & 63;
  const int lg = l >> 4, lr = l & 15;
  const int wr = w >> 1, wc = w & 1;
  // staging map: chunk c -> row=c>>2, 16B-unit u=c&3; source unit pre-swizzled
  const int c1 = tid + 256;
  const int r0 = tid >> 2, k0 = ((tid & 3) ^ ((r0 >> 1) & 3)) << 3;
  const int r1 = c1 >> 2,  k1 = ((c1 & 3) ^ ((r1 >> 1) & 3)) << 3;
  const short* pA0 = A + (size_t)(m0 + r0) * DIM + k0;
  const short* pA1 = A + (size_t)(m0 + r1) * DIM + k1;
  const short* pB0 = Bt + (size_t)(n0 + r0) * DIM + k0;
  const short* pB1 = Bt + (size_t)(n0 + r1) * DIM + k1;
  short* A0 = As;            short* B0 = Bs;
  short* A1 = As + 4096;     short* B1 = Bs + 4096;
  short* A2 = As + 8192;     short* B2 = Bs + 8192;

  // prologue: stage tiles 0 and 1
  STAGE4(A0, B0);
  STAGE4(A1, B1);

  // 64 K-tiles total: 20x3 main + 4 peeled
  for (int it = 0; it < 20; ++it) {
    TILE(A0, B0, A2, B2, true, "4");
    TILE(A1, B1, A0, B0, true, "4");
    TILE(A2, B2, A1, B1, true, "4");
  }
  TILE(A0, B0, A2, B2, true,  "4");  // t=60, stage t=62
  TILE(A1, B1, A0, B0, true,  "4");  // t=61, stage t=63
  TILE(A2, B2, A0, B0, false, "4");  // t=62
  TILE(A0, B0, A1, B1, false, "0");  // t=63
}

__device__ __forceinline__ int2 xcd_swizzle(int nwg) {
  int id = blockIdx.y * gridDim.x + blockIdx.x;
  int swz = (id & 7) * (nwg >> 3) + (id >> 3);
  return make_int2(swz % gridDim.x, swz / gridDim.x);
}

// ---------------- fused QKV projection ----------------
__global__ void __launch_bounds__(256, 3)
gemm_qkv_kernel(const short* __restrict__ A,
                const short* __restrict__ wqt, const short* __restrict__ wkt,
                const short* __restrict__ wvt,
                short* __restrict__ q_ws, short* __restrict__ k_ws, short* __restrict__ v_ws,
                const float* __restrict__ ct, const float* __restrict__ st) {
  __shared__ __align__(16) short As[12288];
  __shared__ __align__(16) short Bs[12288];
  int2 bxy = xcd_swizzle(24 * 32);
  const int n0g = bxy.x * 128;
  const int m0 = bxy.y * 128;
  int mode, n0;
  const short* Bt;
  short* outp;
  if (n0g < 2048)      { mode = 1; Bt = wqt; n0 = n0g;        outp = q_ws; }
  else if (n0g < 2560) { mode = 2; Bt = wkt; n0 = n0g - 2048; outp = k_ws; }
  else                 { mode = 3; Bt = wvt; n0 = n0g - 2560; outp = v_ws; }

  f32x4 acc[4][4] = {};
  gemm_mainloop(A, Bt, m0, n0, As, Bs, acc);

  const int tid = threadIdx.x;
  const int w = tid >> 6, l = tid & 63;
  const int lg = l >> 4, lr = l & 15;
  const int wr = w >> 1, wc = w & 1;
  const int mrow0 = m0 + wr * 64;
  const int ncol0 = n0 + wc * 64;
#pragma unroll
  for (int mt = 0; mt < 4; ++mt)
#pragma unroll
    for (int nt = 0; nt < 4; ++nt)
#pragma unroll
      for (int i = 0; i < 4; ++i) {
        int m = mrow0 + mt * 16 + lg * 4 + i;
        int n = ncol0 + nt * 16 + lr;
        float v = acc[mt][nt][i];
        int b = m >> 11, s = m & (SEQ - 1);
        int h = n >> 6, d = n & 63;
        if (mode == 3) {
          outp[((size_t)(b * NKV + h) * HD + d) * SEQ + s] = f2bf(v);
        } else {
          float p = __shfl_xor(v, 1);
          float cs = ct[(s << 5) + (d >> 1)];
          float sn = st[(s << 5) + (d >> 1)];
          float r = ((d & 1) == 0) ? (v * cs - p * sn) : (p * sn + v * cs);
          if (mode == 1) {
            r *= QSCALE;  // 1/sqrt(HD) * log2(e): softmax done in exp2 domain
            outp[((size_t)(b * NH + h) * SEQ + s) * HD + d] = f2bf(r);
          } else {
            outp[((size_t)(b * NKV + h) * SEQ + s) * HD + d] = f2bf(r);
          }
        }
      }
}

// ---------------- O projection (f32 out) ----------------
__global__ void __launch_bounds__(256, 3)
gemm_o_kernel(const short* __restrict__ A, const short* __restrict__ Bt,
              float* __restrict__ out) {
  __shared__ __align__(16) short As[12288];
  __shared__ __align__(16) short Bs[12288];
  int2 bxy = xcd_swizzle(16 * 32);
  const int m0 = bxy.y * 128, n0 = bxy.x * 128;
  f32x4 acc[4][4] = {};
  gemm_mainloop(A, Bt, m0, n0, As, Bs, acc);
  const int tid = threadIdx.x;
  const int w = tid >> 6, l = tid & 63;
  const int lg = l >> 4, lr = l & 15;
  const int wr = w >> 1, wc = w & 1;
#pragma unroll
  for (int mt = 0; mt < 4; ++mt)
#pragma unroll
    for (int nt = 0; nt < 4; ++nt)
#pragma unroll
      for (int i = 0; i < 4; ++i) {
        int m = m0 + wr * 64 + mt * 16 + lg * 4 + i;
        int n = n0 + wc * 64 + nt * 16 + lr;
        out[(size_t)m * DIM + n] = acc[mt][nt][i];
      }
}

// ---------------- flash attention (swapped QK^T, GQA, causal, exp2 domain) ----------------
// Q: [b][h][s][d] bf16 (pre-scaled by QSCALE), K: [b][kvh][s][d], V: [b][kvh][d][s]
// O: [b][s][h*HD+d] bf16
// Blocks process q-tiles {x, 31-x} -> uniform 33 KV tiles per block.
// 3-buffer stage-t+2 pipeline with counted vmcnt; softmax in shifted exp2
// domain (QK^T seeded with C = -m_run); row-sum via ones-MFMA; defer-max.
__global__ void __launch_bounds__(256, 3)
attn_fwd_kernel(const short* __restrict__ Q, const short* __restrict__ K,
                const short* __restrict__ V, short* __restrict__ O) {
  __shared__ __align__(16) short Ks[3][4096];  // [64 keys][64 dims], xor-swizzled
  __shared__ __align__(16) short Vs[3][4096];  // [64 dims][64 keys], xor-swizzled
  const int tid = threadIdx.x;
  const int w = tid >> 6, l = tid & 63;
  const int lg = l >> 4, lr = l & 15;
  const int h = blockIdx.y;
  const int b = blockIdx.z;
  const int kvh = h >> 2;
  const int lh = lg >> 1, sub = (lg & 1) << 2;

  const short* kbase = K + (size_t)(b * NKV + kvh) * SEQ * HD;
  const short* vbase = V + (size_t)(b * NKV + kvh) * HD * SEQ;

  const int c1 = tid + 256;
  const int r0 = tid >> 3, e0 = ((tid & 7) ^ (r0 & 7)) << 3;
  const int r1 = c1 >> 3, e1 = ((c1 & 7) ^ (r1 & 7)) << 3;

  short8 ones;
#pragma unroll
  for (int i = 0; i < 8; ++i) ones[i] = (short)0x3F80;  // bf16 1.0

#define ASTAGE(kvt, KB, VB) do { const int kv_ = (kvt) * 64;                  \
    GLD16(kbase + (size_t)(kv_ + r0) * HD + e0, (KB) + w * 512);              \
    GLD16(kbase + (size_t)(kv_ + r1) * HD + e1, (KB) + 2048 + w * 512);       \
    GLD16(vbase + (size_t)r0 * SEQ + kv_ + e0, (VB) + w * 512);               \
    GLD16(vbase + (size_t)r1 * SEQ + kv_ + e1, (VB) + 2048 + w * 512); } while (0)

  for (int qi = 0; qi < 2; ++qi) {
    const int qblk = (qi == 0) ? (int)blockIdx.x : (31 - (int)blockIdx.x);
    const int q0 = qblk * 64;
    const int qrow = q0 + w * 16 + lr;  // this lane's q column (swapped layout)

    const short* qptr = Q + ((size_t)(b * NH + h) * SEQ + qrow) * HD;
    short8 qf0 = *(const short8*)(qptr + (lg << 3));
    short8 qf1 = *(const short8*)(qptr + 32 + (lg << 3));

    float m_run = 0.f;       // running max in log2 domain (defer-max; 0-seed is safe)
    f32x4 oacc[4] = {};
    f32x4 lacc = {};         // row-sums, same row layout as oacc

    short* kb0 = Ks[0]; short* kb1 = Ks[1]; short* kb2 = Ks[2];
    short* vb0 = Vs[0]; short* vb1 = Vs[1]; short* vb2 = Vs[2];

    ASTAGE(0, kb0, vb0);
    if (qblk >= 1) ASTAGE(1, kb1, vb1);

    for (int t = 0; t <= qblk; ++t) {
      if (t < qblk) asm volatile("s_waitcnt vmcnt(4)" ::: "memory");
      else          asm volatile("s_waitcnt vmcnt(0)" ::: "memory");
      __builtin_amdgcn_s_barrier();
      __builtin_amdgcn_sched_barrier(0);
      if (t + 2 <= qblk) ASTAGE(t + 2, kb2, vb2);

      const short* ks = kb0;
      const short* vs = vb0;
      const int kv0 = t * 64;

      // hoist all K fragments (8 x b128) and V fragments (16 x b64)
      short8 ka[4][2];
#pragma unroll
      for (int t4 = 0; t4 < 4; ++t4) {
        int row = t4 * 16 + lr, rx = row & 7;
        ka[t4][0] = *(const short8*)&ks[row * 64 + ((lg ^ rx) << 3)];
        ka[t4][1] = *(const short8*)&ks[row * 64 + (((4 + lg) ^ rx) << 3)];
      }
      short8 vbf[4][2];
#pragma unroll
      for (int nt = 0; nt < 4; ++nt) {
        int row = nt * 16 + lr, rx = row & 7;
#pragma unroll
        for (int ks_ = 0; ks_ < 2; ++ks_) {
          union { short8 s8; short4v hh[2]; } u;
          u.hh[0] = *(const short4v*)&vs[row * 64 + (((4 * ks_ + lh) ^ rx) << 3) + sub];
          u.hh[1] = *(const short4v*)&vs[row * 64 + (((4 * ks_ + 2 + lh) ^ rx) << 3) + sub];
          vbf[nt][ks_] = u.s8;
        }
      }

      // S' = K*Q - m_run  (C seeded with -m_run; col=q matches lane layout)
      f32x4 sacc[4];
      {
        f32x4 seed;
        seed[0] = -m_run; seed[1] = -m_run; seed[2] = -m_run; seed[3] = -m_run;
        __builtin_amdgcn_s_setprio(1);
#pragma unroll
        for (int t4 = 0; t4 < 4; ++t4) {
          f32x4 z = __builtin_amdgcn_mfma_f32_16x16x32_bf16(ka[t4][0], qf0, seed, 0, 0, 0);
          sacc[t4] = __builtin_amdgcn_mfma_f32_16x16x32_bf16(ka[t4][1], qf1, z, 0, 0, 0);
        }
        __builtin_amdgcn_s_setprio(0);
      }

      if (t == qblk) {  // diagonal tile: causal mask
#pragma unroll
        for (int t4 = 0; t4 < 4; ++t4)
#pragma unroll
          for (int i = 0; i < 4; ++i)
            if (kv0 + t4 * 16 + lg * 4 + i > qrow) sacc[t4][i] = -__builtin_inff();
      }

      // tile max in shifted domain (max3-friendly triplet tree)
      float a0 = fmaxf(fmaxf(sacc[0][0], sacc[0][1]), sacc[0][2]);
      float a1 = fmaxf(fmaxf(sacc[0][3], sacc[1][0]), sacc[1][1]);
      float a2 = fmaxf(fmaxf(sacc[1][2], sacc[1][3]), sacc[2][0]);
      float a3 = fmaxf(fmaxf(sacc[2][1], sacc[2][2]), sacc[2][3]);
      float a4 = fmaxf(fmaxf(sacc[3][0], sacc[3][1]), sacc[3][2]);
      float tm = fmaxf(fmaxf(fmaxf(a0, a1), a2), fmaxf(fmaxf(a3, a4), sacc[3][3]));
      tm = fmaxf(tm, __shfl_xor(tm, 16));
      tm = fmaxf(tm, __shfl_xor(tm, 32));

      // defer-max: rescale only when shifted max exceeds THR (P <= 2^12 otherwise)
      if (!__all(tm <= 12.0f)) {
        float d = fmaxf(tm, 0.f);
        float alpha = EXP2(-d);
        float av0 = __shfl(alpha, (lg << 2));
        float av1 = __shfl(alpha, (lg << 2) | 1);
        float av2 = __shfl(alpha, (lg << 2) | 2);
        float av3 = __shfl(alpha, (lg << 2) | 3);
#pragma unroll
        for (int nt = 0; nt < 4; ++nt) {
          oacc[nt][0] *= av0; oacc[nt][1] *= av1;
          oacc[nt][2] *= av2; oacc[nt][3] *= av3;
        }
        lacc[0] *= av0; lacc[1] *= av1; lacc[2] *= av2; lacc[3] *= av3;
        m_run += d;
#pragma unroll
        for (int t4 = 0; t4 < 4; ++t4)
#pragma unroll
          for (int i = 0; i < 4; ++i) sacc[t4][i] -= d;
      }

      // P = exp2(S') packed straight to bf16 fragments (k-bijection feeds PV A)
      union { short8 s8; uint32_t u[4]; } pa0, pa1;
      pa0.u[0] = cvtpk_bf16(EXP2(sacc[0][0]), EXP2(sacc[0][1]));
      pa0.u[1] = cvtpk_bf16(EXP2(sacc[0][2]), EXP2(sacc[0][3]));
      pa0.u[2] = cvtpk_bf16(EXP2(sacc[1][0]), EXP2(sacc[1][1]));
      pa0.u[3] = cvtpk_bf16(EXP2(sacc[1][2]), EXP2(sacc[1][3]));
      pa1.u[0] = cvtpk_bf16(EXP2(sacc[2][0]), EXP2(sacc[2][1]));
      pa1.u[1] = cvtpk_bf16(EXP2(sacc[2][2]), EXP2(sacc[2][3]));
      pa1.u[2] = cvtpk_bf16(EXP2(sacc[3][0]), EXP2(sacc[3][1]));
      pa1.u[3] = cvtpk_bf16(EXP2(sacc[3][2]), EXP2(sacc[3][3]));

      // O += P * V; l += P * ones  (row-sum via MFMA, replaces lsum adds + shfls)
      __builtin_amdgcn_s_setprio(1);
#pragma unroll
      for (int nt = 0; nt < 4; ++nt) {
        oacc[nt] = __builtin_amdgcn_mfma_f32_16x16x32_bf16(pa0.s8, vbf[nt][0], oacc[nt], 0, 0, 0);
        oacc[nt] = __builtin_amdgcn_mfma_f32_16x16x32_bf16(pa1.s8, vbf[nt][1], oacc[nt], 0, 0, 0);
      }
      lacc = __builtin_amdgcn_mfma_f32_16x16x32_bf16(pa0.s8, ones, lacc, 0, 0, 0);
      lacc = __builtin_amdgcn_mfma_f32_16x16x32_bf16(pa1.s8, ones, lacc, 0, 0, 0);
      __builtin_amdgcn_s_setprio(0);

      short* tk = kb0; kb0 = kb1; kb1 = kb2; kb2 = tk;
      short* tv = vb0; vb0 = vb1; vb1 = vb2; vb2 = tv;
    }

    // epilogue: normalize and store (l already in oacc row layout, no shfl)
    float linv0 = 1.f / lacc[0], linv1 = 1.f / lacc[1];
    float linv2 = 1.f / lacc[2], linv3 = 1.f / lacc[3];
#pragma unroll
    for (int nt = 0; nt < 4; ++nt) {
      int d = nt * 16 + lr;
      int qb = q0 + w * 16 + lg * 4;
      O[(size_t)(b * SEQ + qb + 0) * DIM + h * HD + d] = f2bf(oacc[nt][0] * linv0);
      O[(size_t)(b * SEQ + qb + 1) * DIM + h * HD + d] = f2bf(oacc[nt][1] * linv1);
      O[(size_t)(b * SEQ + qb + 2) * DIM + h * HD + d] = f2bf(oacc[nt][2] * linv2);
      O[(size_t)(b * SEQ + qb + 3) * DIM + h * HD + d] = f2bf(oacc[nt][3] * linv3);
    }
    __syncthreads();  // protect LDS buffers before next q-tile's prologue staging
  }
#undef ASTAGE
}

// ---------------- launch ----------------

extern "C" void kernel_launch(void* const* d_in, const int* in_sizes, int n_in,
                              void* d_out, int out_size, void* d_ws, size_t ws_size,
                              hipStream_t stream) {
  const float* x  = (const float*)d_in[0];
  const float* wq = (const float*)d_in[1];
  const float* wk = (const float*)d_in[2];
  const float* wv = (const float*)d_in[3];
  const float* wo = (const float*)d_in[4];
  float* out = (float*)d_out;
  char* ws = (char*)d_ws;

  // workspace layout (bytes); attn aliases x_bf (dead after QKV GEMM),
  // wo_t aliases wq_t (dead after QKV GEMM)
  short* x_bf  = (short*)(ws + 0);          // 16 MB  [4096][2048]
  short* attn  = (short*)(ws + 0);          // alias of x_bf
  short* q_ws  = (short*)(ws + 16777216);   // 16 MB  [b][h][s][d]
  short* k_ws  = (short*)(ws + 33554432);   // 4 MB   [b][kvh][s][d]
  short* v_ws  = (short*)(ws + 37748736);   // 4 MB   [b][kvh][d][s]
  short* wq_t  = (short*)(ws + 41943040);   // 8 MB   [N][K]
  short* wo_t  = (short*)(ws + 41943040);   // alias of wq_t
  short* wk_t  = (short*)(ws + 50331648);   // 2 MB
  short* wv_t  = (short*)(ws + 52428800);   // 2 MB
  float* ct    = (float*)(ws + 54525952);   // 256 KB
  float* st    = (float*)(ws + 54788096);   // 256 KB
  (void)ws_size; (void)in_sizes; (void)n_in; (void)out_size;

  dim3 tb(32, 8);
  cvt_x_kernel<<<8192, 256, 0, stream>>>(x, x_bf, 2097152);
  transpose_bf_kernel<<<dim3(64, 64), tb, 0, stream>>>(wq, wq_t, DIM, 2048);
  transpose_bf_kernel<<<dim3(16, 64), tb, 0, stream>>>(wk, wk_t, DIM, 512);
  transpose_bf_kernel<<<dim3(16, 64), tb, 0, stream>>>(wv, wv_t, DIM, 512);
  rope_tab_kernel<<<256, 256, 0, stream>>>(ct, st);

  gemm_qkv_kernel<<<dim3(24, 32), 256, 0, stream>>>(x_bf, wq_t, wk_t, wv_t,
                                                    q_ws, k_ws, v_ws, ct, st);

  attn_fwd_kernel<<<dim3(16, 32, 2), 256, 0, stream>>>(q_ws, k_ws, v_ws, attn);

  transpose_bf_kernel<<<dim3(64, 64), tb, 0, stream>>>(wo, wo_t, DIM, 2048);
  gemm_o_kernel<<<dim3(16, 32), 256, 0, stream>>>(attn, wo_t, out);
}